// Round 7
// baseline (164.610 us; speedup 1.0000x reference)
//
#include <hip/hip_runtime.h>
#include <math.h>

namespace {
constexpr int kUnits = 128;
constexpr int kSteps = 2048;
constexpr int kBatch = 32;
constexpr int kSeg = 32;                       // linearization window (validated)
constexpr int kNSeg = kSteps / kSeg;           // 64 segments per chain
constexpr int kUBlk = 8;                       // units (chains) per block
constexpr int kUPT = 1;                        // units per thread
constexpr int kUG = kUBlk / kUPT;              // 8 u-groups
constexpr int kThreads = kUG * kNSeg;          // 512 threads/block
constexpr int kBlocks = kBatch * (kUnits / kUBlk);  // 512 blocks -> 2/CU
constexpr int kGrp = 16;                       // scan groups
constexpr int kGrpSeg = kNSeg / kGrp;          // 4 segments per group
constexpr int kPad = kUBlk + 1;                // LDS pad
constexpr double kDT = 1.0 / 173.61;
constexpr double kTwoPi = 6.283185307179586;
constexpr double kInv2Pi = 1.0 / kTwoPi;
constexpr size_t kChainElems = (size_t)kSteps * kUnits;

// Zero-input deterministic r trajectory (identical for every chain) and the
// linear growth factors G_t = 1 + (1 - 3*beta*rbar^2)*dt, at compile time.
struct Tables {
  float G[kSteps];
  float Gseg[kNSeg];   // product of G over each segment
  float Gg[kGrp];      // product of Gseg over each scan group
  float rbar0[kNSeg];  // rbar at segment starts
};
constexpr Tables make_tables() {
  Tables tb{};
  double r = 1.0;
  for (int t = 0; t < kSteps; ++t) {
    if (t % kSeg == 0) tb.rbar0[t / kSeg] = (float)r;
    tb.G[t] = (float)(1.0 + (1.0 - 0.03 * r * r) * kDT);
    r = r + (1.0 - 0.01 * r * r) * r * kDT;
  }
  for (int s = 0; s < kNSeg; ++s) {
    double p = 1.0;
    for (int j = 0; j < kSeg; ++j) p *= (double)tb.G[s * kSeg + j];
    tb.Gseg[s] = (float)p;
  }
  for (int g = 0; g < kGrp; ++g) {
    double p = 1.0;
    for (int s = 0; s < kGrpSeg; ++s) p *= (double)tb.Gseg[g * kGrpSeg + s];
    tb.Gg[g] = (float)p;
  }
  return tb;
}
}  // namespace

__constant__ Tables kTab = make_tables();

// Fused linearized-scan Hopf solver.
//  512 blocks x 512 threads, 2 blocks/CU co-resident so one block's store
//  phase overlaps the other's load phase (R6 was 1 block/CU: phases serial).
//  phase1: per-thread (segment x 1 unit) compose linear (delta,rho) maps -> LDS
//  phase2: 3-level scan (4+16+4) of 64 segment maps per chain in LDS
//  phase3: exact nonlinear replay from register-cached X, nontemporal stores.
__global__ __launch_bounds__(kThreads, 4)
void hopf_fused(const float* __restrict__ Xr, const float* __restrict__ Xi,
                const float* __restrict__ Om,
                float* __restrict__ Zr, float* __restrict__ Zi) {
  __shared__ float sG[kNSeg][kPad];   // maps, then delta0 after phase2
  __shared__ float sH[kNSeg][kPad];   // maps, then rho0 after phase2
  __shared__ float sP[kNSeg][kPad];
  __shared__ float sQ[kNSeg][kPad];
  __shared__ float cG[kGrp][kPad], cH[kGrp][kPad], cP[kGrp][kPad], cQ[kGrp][kPad];
  __shared__ float pD[kGrp][kPad], pR[kGrp][kPad];
  __shared__ float cwS[kUBlk], swS[kUBlk];

  const int tid = threadIdx.x;
  const int ug = tid & (kUG - 1);     // 0..7  (unit within block)
  const int seg = tid >> 3;           // 0..63 (segment)
  // Swizzle so the two sibling blocks sharing 64B cache-line rows (uq pair)
  // get ids differing by 8 -> same XCD (id%8) -> same L2 for the line halves.
  const int xg = blockIdx.x & 7;
  const int half = (blockIdx.x >> 3) & 1;
  const int b = (blockIdx.x >> 4) & 31;
  const int uq = xg * 2 + half;       // 0..15
  const int u0 = uq * kUBlk + ug;
  const int t0 = seg * kSeg;

  // per-unit rotation constants, f64 once per block (8 lanes)
  if (tid < kUBlk) {
    const double wdt = (double)Om[uq * kUBlk + tid] * kDT;
    double sd, cd;
    sincos(wdt, &sd, &cd);
    cwS[tid] = (float)cd;
    swS[tid] = (float)sd;
  }

  // accurate segment-start angle for phase1 (f64 reduce, f32 sincos)
  const double wdt_d = (double)Om[u0] * kDT;
  float c0, s0;
  {
    const double ang = wdt_d * (double)t0;
    const double kk = rint(ang * kInv2Pi);
    const float th = (float)fma(-kk, kTwoPi, ang);
    __sincosf(th, &s0, &c0);
  }
  __syncthreads();
  const float cw = cwS[ug];
  const float sw = swS[ug];

  // ---- load this thread's segment inputs ONCE into registers ----
  const size_t base = ((size_t)b * kSteps + t0) * (size_t)kUnits + u0;
  float xr[kSeg], xi[kSeg];
#pragma unroll
  for (int j = 0; j < kSeg; ++j) {
    xr[j] = Xr[base + (size_t)j * kUnits];
    xi[j] = Xi[base + (size_t)j * kUnits];
  }

  // ---- phase 1: compose the segment's linear map ----
  const float cdt = (float)(0.1 * kDT);
  float gr = 1.f, hr = 0.f, pr = 0.f, qr = 0.f;
#pragma unroll
  for (int j = 0; j < kSeg; ++j) {
    const float Ge = kTab.G[t0 + j];
    const float axi = cdt * xi[j];
    const float axr = cdt * xr[j];
    const float ge = fmaf(-axi, c0, 1.f);  // 1 - c*xi*cos(phi0)
    const float he = -axi * s0;            // -c*xi*sin(phi0)
    const float pe = -axr * s0;            // -c*xr*sin(phi0)
    const float qe = axr * c0;             //  c*xr*cos(phi0)
    const float g2 = gr * ge;
    const float h2 = fmaf(ge, hr, he);
    const float p2 = fmaf(pe, gr, Ge * pr);
    const float q2 = fmaf(pe, hr, fmaf(Ge, qr, qe));
    gr = g2; hr = h2; pr = p2; qr = q2;
    const float c1 = fmaf(cw, c0, -(sw * s0));
    const float s1 = fmaf(cw, s0, sw * c0);
    c0 = c1; s0 = s1;
  }
  sG[seg][ug] = gr;
  sH[seg][ug] = hr;
  sP[seg][ug] = pr;
  sQ[seg][ug] = qr;
  __syncthreads();

  // ---- phase 2, level 1: compose 4-segment groups (128 threads) ----
  if (tid < kUBlk * kGrp) {
    const int ch = tid & (kUBlk - 1);
    const int gb = tid >> 3;
    float g = 1.f, h = 0.f, p = 0.f, q = 0.f;
#pragma unroll
    for (int i = 0; i < kGrpSeg; ++i) {
      const int sg = gb * kGrpSeg + i;
      const float mg = sG[sg][ch], mh = sH[sg][ch];
      const float mp = sP[sg][ch], mq = sQ[sg][ch];
      const float Gs = kTab.Gseg[sg];
      const float g2 = mg * g;
      const float h2 = fmaf(mg, h, mh);
      const float p2 = fmaf(mp, g, Gs * p);
      const float q2 = fmaf(mp, h, fmaf(Gs, q, mq));
      g = g2; h = h2; p = p2; q = q2;
    }
    cG[gb][ch] = g; cH[gb][ch] = h; cP[gb][ch] = p; cQ[gb][ch] = q;
  }
  __syncthreads();

  // ---- phase 2, level 2: scan 16 group maps per chain (8 threads) ----
  if (tid < kUBlk) {
    const int ch = tid;
    float d = 0.f, rho = 0.f;
#pragma unroll
    for (int gb = 0; gb < kGrp; ++gb) {
      pD[gb][ch] = d;
      pR[gb][ch] = rho;
      const float g = cG[gb][ch], h = cH[gb][ch];
      const float p = cP[gb][ch], q = cQ[gb][ch];
      const float Gs = kTab.Gg[gb];
      const float dn = fmaf(g, d, h);
      const float rn = fmaf(p, d, fmaf(Gs, rho, q));
      d = dn; rho = rn;
    }
  }
  __syncthreads();

  // ---- phase 2, level 3: expand within groups; overwrite sG/sH with
  // per-segment start states (delta0, rho0) ----
  if (tid < kUBlk * kGrp) {
    const int ch = tid & (kUBlk - 1);
    const int gb = tid >> 3;
    float d = pD[gb][ch], rho = pR[gb][ch];
#pragma unroll
    for (int i = 0; i < kGrpSeg; ++i) {
      const int sg = gb * kGrpSeg + i;
      const float mg = sG[sg][ch], mh = sH[sg][ch];
      const float mp = sP[sg][ch], mq = sQ[sg][ch];
      sG[sg][ch] = d;
      sH[sg][ch] = rho;
      const float Gs = kTab.Gseg[sg];
      const float dn = fmaf(mg, d, mh);
      const float rn = fmaf(mp, d, fmaf(Gs, rho, mq));
      d = dn; rho = rn;
    }
  }
  __syncthreads();

  // ---- phase 3: exact nonlinear replay from register-cached X ----
  float c, s, r;
  {
    const float delta = sG[seg][ug];
    const float rho = sH[seg][ug];
    const double ang = wdt_d * (double)t0 + (double)delta;
    const double kk = rint(ang * kInv2Pi);
    const float th = (float)fma(-kk, kTwoPi, ang);
    __sincosf(th, &s, &c);
    r = kTab.rbar0[seg] + rho;
  }

  const float DTf = (float)kDT;
  const float nscale = -(0.1f * DTf);
  const float c01dt = 0.1f * DTf;
#pragma unroll
  for (int j = 0; j < kSeg; ++j) {
    // rotate (c,s) by (w*dt + eps), eps = -0.1*dt*xi*sin(phi)
    const float eps = (xi[j] * nscale) * s;
    const float A = fmaf(-sw, eps, cw);
    const float B = fmaf(cw, eps, sw);
    const float c2 = fmaf(A, c, -(B * s));
    const float s2 = fmaf(A, s, B * c);
    // r update with OLD c,r (reference order)
    const float rr = r * r;
    const float om1 = fmaf(-0.01f, rr, 1.f);
    const float racc = fmaf(xr[j] * c, c01dt, r);
    r = fmaf(om1 * r, DTf, racc);
    c = c2; s = s2;
    __builtin_nontemporal_store(r * c, Zr + base + (size_t)j * kUnits);
    __builtin_nontemporal_store(r * s, Zi + base + (size_t)j * kUnits);
  }
}

extern "C" void kernel_launch(void* const* d_in, const int* in_sizes, int n_in,
                              void* d_out, int out_size, void* d_ws, size_t ws_size,
                              hipStream_t stream) {
  const float* Xr = (const float*)d_in[0];
  const float* Xi = (const float*)d_in[1];
  const float* Om = (const float*)d_in[2];
  float* Zr = (float*)d_out;
  float* Zi = (float*)d_out + (size_t)kBatch * kChainElems;

  hipLaunchKernelGGL(hopf_fused, dim3(kBlocks), dim3(kThreads), 0, stream,
                     Xr, Xi, Om, Zr, Zi);
}